// Round 1
// 477.074 us; speedup vs baseline: 1.0895x; 1.0895x over previous
//
#include <hip/hip_runtime.h>
#include <cstdint>

#define INDIM 1024
#define OUTDIM 1024
#define NNZ 65536
#define M_ROWS 50000

typedef __bf16 bf16x8 __attribute__((ext_vector_type(8)));
typedef float f32x4 __attribute__((ext_vector_type(4)));
typedef unsigned int u32x4 __attribute__((ext_vector_type(4)));

// ---------------- scatter nnz values into dense fp32 W [OUTDIM][INDIM] ----------------
__global__ void scatter_w_kernel(const float* __restrict__ vals,
                                 const int* __restrict__ edge,
                                 float* __restrict__ Wf) {
    int e = blockIdx.x * blockDim.x + threadIdx.x;
    if (e < NNZ) {
        int r = edge[e];        // row  (output dim)
        int c = edge[NNZ + e];  // col  (input dim)
        atomicAdd(&Wf[r * INDIM + c], vals[e]);  // duplicates accumulate (matches .at[].add)
    }
}

// ---------------- fp32 W -> bf16 W (round via +0x8000 truncate) -----------------------
__global__ void cvt_w_kernel(const float* __restrict__ Wf,
                             unsigned short* __restrict__ Wb) {
    int i = blockIdx.x * blockDim.x + threadIdx.x;
    unsigned u = __builtin_bit_cast(unsigned, Wf[i]) + 0x8000u;
    Wb[i] = (unsigned short)(u >> 16);
}

// pack two fp32 -> one u32 holding two bf16 (a in low half = lower k index)
__device__ __forceinline__ unsigned pack_bf16x2(float a, float b) {
    unsigned ua = __builtin_bit_cast(unsigned, a) + 0x8000u;
    unsigned ub = __builtin_bit_cast(unsigned, b) + 0x8000u;
    return (ua >> 16) | (ub & 0xffff0000u);
}

// ---------------- fp32 X -> bf16 Xb, vectorized: 8 elems/thread -----------------------
// 50000*1024 = 51.2M elems; 25000 blocks x 256 thr x 8 = exact cover.
__global__ void cvt_x_kernel(const float* __restrict__ X,
                             unsigned short* __restrict__ Xb) {
    long i = ((long)blockIdx.x * blockDim.x + threadIdx.x) * 8;
    f32x4 a = *(const f32x4*)(X + i);
    f32x4 b = *(const f32x4*)(X + i + 4);
    u32x4 p;
    p.x = pack_bf16x2(a.x, a.y);
    p.y = pack_bf16x2(a.z, a.w);
    p.z = pack_bf16x2(b.x, b.y);
    p.w = pack_bf16x2(b.z, b.w);
    *(u32x4*)(Xb + i) = p;
}

__device__ __forceinline__ void async_copy16(const void* g, void* l) {
    __builtin_amdgcn_global_load_lds(
        (const __attribute__((address_space(1))) void*)g,
        (__attribute__((address_space(3))) void*)l, 16, 0, 0);
}

// ---------------- fast GEMM: out = bf16(X) @ Wb^T + bias (both operands async) --------
// m97 structure: 128x128 tile, BK=32, 4 waves (2x2), 4x4 frags of 16x16x32 per wave.
// Both A and B staged via global_load_lds (16B) with pre-swizzled SOURCE + linear LDS
// dest; frag ds_read applies the same XOR swizzle -> uniform 2-way (free) bank access.
// XCD-aware bid remap: the 8 n-blocks of one m-panel share bid%8 -> same XCD L2.
__global__ void __launch_bounds__(256, 4)
gemm_bb_kernel(const unsigned short* __restrict__ Xb,
               const unsigned short* __restrict__ Wb,
               const float* __restrict__ bias,
               float* __restrict__ out) {
    __shared__ unsigned short As[128 * 32];  // 8 KB, swizzled chunks
    __shared__ unsigned short Bs[128 * 32];  // 8 KB, swizzled chunks

    const int t = threadIdx.x;
    const int w = t >> 6;        // wave id 0..3
    const int l = t & 63;        // lane
    const int wr = w >> 1;       // wave row group (0..1) -> 64 rows
    const int wc = w & 1;        // wave col group (0..1) -> 64 cols
    const int quad = l >> 4;     // 0..3  (= data chunk index for frag reads)
    const int lr = l & 15;       // 0..15

    // ---- XCD-aware block remap ----
    const int bid = blockIdx.x;  // 0..3127
    int m_t, n_t;
    if (bid < 3072) {
        m_t = ((bid >> 6) << 3) + (bid & 7);  // 0..383
        n_t = (bid >> 3) & 7;
    } else {
        int r = bid - 3072;                   // 0..55
        m_t = 384 + (r >> 3);                 // 384..390
        n_t = r & 7;
    }
    const int m0 = m_t * 128;
    const int n0 = n_t * 128;

    // ---- staging source permutation (identical for A and B paths) ----
    // chunk c_idx (0..511) lands linearly in LDS; pick the matching DATA chunk from the
    // row so that phys chunk pphys == pdata ^ ((row>>1)&3).
    int row_[2], soff_[2], arow_[2];
#pragma unroll
    for (int i = 0; i < 2; i++) {
        int c_idx = i * 256 + t;             // phys chunk 0..511
        int row = c_idx >> 2;                // tile row 0..127
        int pphys = c_idx & 3;
        int pdata = pphys ^ ((row >> 1) & 3);
        row_[i] = row;
        soff_[i] = pdata * 8;                // shorts
        int ar = m0 + row;
        arow_[i] = (ar < M_ROWS) ? ar : (M_ROWS - 1);  // clamp tail (masked at store)
    }

    f32x4 acc[4][4];
#pragma unroll
    for (int i = 0; i < 4; i++)
#pragma unroll
        for (int j = 0; j < 4; j++) acc[i][j] = (f32x4)0.0f;

    float biasv[4];
#pragma unroll
    for (int j = 0; j < 4; j++) biasv[j] = bias[n0 + wc * 64 + j * 16 + lr];

    for (int kt = 0; kt < INDIM; kt += 32) {
        // ---- stage A (8 KB) + B (8 KB) fully async ----
#pragma unroll
        for (int i = 0; i < 2; i++) {
            async_copy16(Xb + (long)arow_[i] * INDIM + kt + soff_[i],
                         (char*)As + (size_t)(i * 256 + w * 64) * 16);
            async_copy16(Wb + (long)(n0 + row_[i]) * INDIM + kt + soff_[i],
                         (char*)Bs + (size_t)(i * 256 + w * 64) * 16);
        }

        __syncthreads();  // drains vmcnt -> LDS tiles ready

        // ---- fragments + 16 MFMA (swizzled reads) ----
        bf16x8 af[4], bfr[4];
#pragma unroll
        for (int i = 0; i < 4; i++) {
            int row = wr * 64 + i * 16 + lr;
            int ph = quad ^ ((row >> 1) & 3);
            af[i] = *(const bf16x8*)(As + row * 32 + ph * 8);
        }
#pragma unroll
        for (int j = 0; j < 4; j++) {
            int row = wc * 64 + j * 16 + lr;
            int ph = quad ^ ((row >> 1) & 3);
            bfr[j] = *(const bf16x8*)(Bs + row * 32 + ph * 8);
        }
#pragma unroll
        for (int i = 0; i < 4; i++)
#pragma unroll
            for (int j = 0; j < 4; j++)
                acc[i][j] = __builtin_amdgcn_mfma_f32_16x16x32_bf16(af[i], bfr[j], acc[i][j], 0, 0, 0);

        __syncthreads();  // protect LDS before next-iter staging
    }

    // ---- epilogue: C/D layout col=lane&15, row=quad*4+reg ----
#pragma unroll
    for (int i = 0; i < 4; i++) {
#pragma unroll
        for (int j = 0; j < 4; j++) {
            int col = n0 + wc * 64 + j * 16 + lr;
#pragma unroll
            for (int r = 0; r < 4; r++) {
                int row = m0 + wr * 64 + i * 16 + quad * 4 + r;
                if (row < M_ROWS) {
                    out[(long)row * OUTDIM + col] = acc[i][j][r] + biasv[j];
                }
            }
        }
    }
}

// ---------------- fallback GEMM (fp32 X, in-loop pack) — previous verified kernel ----
__global__ void __launch_bounds__(256)
gemm_bt_kernel(const float* __restrict__ X,
               const unsigned short* __restrict__ Wb,
               const float* __restrict__ bias,
               float* __restrict__ out) {
    __shared__ unsigned As[128 * 16];        // 128 rows x 32 bf16 (16 u32/row), swizzled
    __shared__ unsigned short Bs[128 * 32];  // 128 rows x 32 bf16, swizzled

    const int t = threadIdx.x;
    const int w = t >> 6;
    const int l = t & 63;
    const int wr = w >> 1;
    const int wc = w & 1;
    const int quad = l >> 4;
    const int lr = l & 15;

    const int bid = blockIdx.x;
    int m_t, n_t;
    if (bid < 3072) {
        m_t = ((bid >> 6) << 3) + (bid & 7);
        n_t = (bid >> 3) & 7;
    } else {
        int r = bid - 3072;
        m_t = 384 + (r >> 3);
        n_t = r & 7;
    }
    const int m0 = m_t * 128;
    const int n0 = n_t * 128;

    const int ar  = t >> 1;
    const int ac0 = (t & 1) * 2;
    const int as_sw = (ar >> 1) & 3;
    int arow = m0 + ar;
    if (arow >= M_ROWS) arow = M_ROWS - 1;
    const float* aptr = X + (long)arow * INDIM + (t & 1) * 16;
    unsigned* as_row = &As[ar * 16];
    const int aph0 = (ac0 ^ as_sw) * 4;
    const int aph1 = ((ac0 + 1) ^ as_sw) * 4;

    f32x4 acc[4][4];
#pragma unroll
    for (int i = 0; i < 4; i++)
#pragma unroll
        for (int j = 0; j < 4; j++) acc[i][j] = (f32x4)0.0f;

    float biasv[4];
#pragma unroll
    for (int j = 0; j < 4; j++) biasv[j] = bias[n0 + wc * 64 + j * 16 + lr];

    int bsrc_off[2];
    int brow_[2];
#pragma unroll
    for (int i = 0; i < 2; i++) {
        int c_idx = i * 256 + t;
        int brow = c_idx >> 2;
        int pphys = c_idx & 3;
        int pdata = pphys ^ ((brow >> 1) & 3);
        brow_[i] = brow;
        bsrc_off[i] = pdata * 8;
    }

    for (int kt = 0; kt < INDIM; kt += 32) {
#pragma unroll
        for (int i = 0; i < 2; i++) {
            const unsigned short* g = Wb + (long)(n0 + brow_[i]) * INDIM + kt + bsrc_off[i];
            char* lbase = (char*)Bs + (size_t)(i * 256 + w * 64) * 16;
            async_copy16(g, lbase);
        }

        const float* ap = aptr + kt;
        f32x4 f0 = *(const f32x4*)(ap);
        f32x4 f1 = *(const f32x4*)(ap + 4);
        f32x4 f2 = *(const f32x4*)(ap + 8);
        f32x4 f3 = *(const f32x4*)(ap + 12);
        u32x4 p0, p1;
        p0.x = pack_bf16x2(f0.x, f0.y);
        p0.y = pack_bf16x2(f0.z, f0.w);
        p0.z = pack_bf16x2(f1.x, f1.y);
        p0.w = pack_bf16x2(f1.z, f1.w);
        p1.x = pack_bf16x2(f2.x, f2.y);
        p1.y = pack_bf16x2(f2.z, f2.w);
        p1.z = pack_bf16x2(f3.x, f3.y);
        p1.w = pack_bf16x2(f3.z, f3.w);
        *(u32x4*)(as_row + aph0) = p0;
        *(u32x4*)(as_row + aph1) = p1;

        __syncthreads();

        bf16x8 af[4], bfr[4];
#pragma unroll
        for (int i = 0; i < 4; i++) {
            int row = wr * 64 + i * 16 + lr;
            int ph = quad ^ ((row >> 1) & 3);
            af[i] = *(const bf16x8*)((const unsigned short*)As + row * 32 + ph * 8);
        }
#pragma unroll
        for (int j = 0; j < 4; j++) {
            int row = wc * 64 + j * 16 + lr;
            int ph = quad ^ ((row >> 1) & 3);
            bfr[j] = *(const bf16x8*)(Bs + row * 32 + ph * 8);
        }
#pragma unroll
        for (int i = 0; i < 4; i++)
#pragma unroll
            for (int j = 0; j < 4; j++)
                acc[i][j] = __builtin_amdgcn_mfma_f32_16x16x32_bf16(af[i], bfr[j], acc[i][j], 0, 0, 0);

        __syncthreads();
    }

#pragma unroll
    for (int i = 0; i < 4; i++) {
#pragma unroll
        for (int j = 0; j < 4; j++) {
            int col = n0 + wc * 64 + j * 16 + lr;
#pragma unroll
            for (int r = 0; r < 4; r++) {
                int row = m0 + wr * 64 + i * 16 + quad * 4 + r;
                if (row < M_ROWS) {
                    out[(long)row * OUTDIM + col] = acc[i][j][r] + biasv[j];
                }
            }
        }
    }
}

extern "C" void kernel_launch(void* const* d_in, const int* in_sizes, int n_in,
                              void* d_out, int out_size, void* d_ws, size_t ws_size,
                              hipStream_t stream) {
    const float* x    = (const float*)d_in[0];
    const float* nnzw = (const float*)d_in[1];
    const float* bias = (const float*)d_in[2];
    const int* edge   = (const int*)d_in[3];
    float* out        = (float*)d_out;

    const size_t wf_bytes = (size_t)OUTDIM * INDIM * 4;   // 4 MB
    const size_t wb_bytes = (size_t)OUTDIM * INDIM * 2;   // 2 MB
    const size_t xb_off   = wf_bytes + wb_bytes;          // 6 MB
    const size_t xb_bytes = (size_t)M_ROWS * INDIM * 2;   // 102.4 MB

    float* Wf          = (float*)d_ws;
    unsigned short* Wb = (unsigned short*)((char*)d_ws + wf_bytes);
    unsigned short* Xb = (unsigned short*)((char*)d_ws + xb_off);

    // ws is poisoned 0xAA before every launch -> zero W accumulator every call
    hipMemsetAsync(Wf, 0, wf_bytes, stream);

    scatter_w_kernel<<<NNZ / 256, 256, 0, stream>>>(nnzw, edge, Wf);
    cvt_w_kernel<<<(OUTDIM * INDIM) / 256, 256, 0, stream>>>(Wf, Wb);

    if (ws_size >= xb_off + xb_bytes) {
        // fast path: pre-convert X to bf16, then fully-async-staged GEMM (m97 structure)
        cvt_x_kernel<<<(M_ROWS * INDIM) / (256 * 8), 256, 0, stream>>>(x, Xb);
        gemm_bb_kernel<<<dim3(3128), 256, 0, stream>>>(Xb, Wb, bias, out);
    } else {
        // fallback: previous verified kernel (fp32 X, in-loop pack)
        gemm_bt_kernel<<<dim3(3128), 256, 0, stream>>>(x, Wb, bias, out);
    }
}